// Round 3
// baseline (255.516 us; speedup 1.0000x reference)
//
#include <hip/hip_runtime.h>
#include <hip/hip_bf16.h>
#include <stdint.h>

using bf16x8 = __attribute__((ext_vector_type(8))) short;
using f32x4  = __attribute__((ext_vector_type(4))) float;

#define N_NODES  50000
#define K1       768
#define D1       512
#define NPAIR    16384
#define NOUT     97
#define NOUT_PAD 112
#define MTILES   391                 // ceil(50000/128)
#define NTILES   4
#define NWG      (MTILES * NTILES)   // 1564
#define WGPX     196                 // ceil(1564/8)

__device__ __forceinline__ uint16_t f2bf(float f) {
    uint32_t u = __builtin_bit_cast(uint32_t, f);
    return (uint16_t)((u + 0x7fffu + ((u >> 16) & 1u)) >> 16);  // RNE
}

// packed RNE f32->bf16 pair (no builtin on gfx950 -> inline asm)
__device__ __forceinline__ uint32_t cvt_pk_bf16(float lo, float hi) {
    uint32_t r;
    asm("v_cvt_pk_bf16_f32 %0, %1, %2" : "=v"(r) : "v"(lo), "v"(hi));
    return r;
}

// ---- convert: W1[768][512] -> W1t bf16 [512][768]; Wp[1024][97] -> Wpt bf16 [112][1024] (zero-pad) ----
__global__ void k_convert(const float* __restrict__ W1, const float* __restrict__ Wp,
                          uint16_t* __restrict__ W1t, uint16_t* __restrict__ Wpt) {
    int idx = blockIdx.x * 256 + threadIdx.x;
    const int n1 = D1 * K1;
    if (idx < n1) {
        int c = idx / K1, k = idx - c * K1;
        W1t[idx] = f2bf(W1[k * D1 + c]);
    } else {
        int j = idx - n1;
        if (j < NOUT_PAD * 1024) {
            int c = j >> 10, k = j & 1023;
            Wpt[j] = (c < NOUT) ? f2bf(Wp[k * NOUT + c]) : (uint16_t)0;
        }
    }
}

// ---- GEMM1: H[50000][512] = relu(A[50000][768] @ W1 + b1) ----
// Barrier-free, LDS-free: each wave loads its MFMA fragments directly from
// global (A fp32 -> in-reg cvt_pk -> bf16; B pre-transposed bf16), 2-deep
// register double-buffer, 128x128 block tile (2x2 waves), XCD-grouped blocks.
__global__ __launch_bounds__(256) void k_gemm1(const float* __restrict__ A,
        const uint16_t* __restrict__ W1t, const float* __restrict__ bias1,
        uint16_t* __restrict__ H) {
    const int bid = blockIdx.x;
    const int tt = (bid & 7) * WGPX + (bid >> 3);
    if (tt >= NWG) return;
    const int m0 = (tt >> 2) * 128, n0 = (tt & 3) * 128;

    const int t = threadIdx.x;
    const int lane = t & 63, wave = t >> 6;
    const int wm = wave >> 1, wn = wave & 1;
    const int cl = lane & 15, kh = lane >> 4;

    // fragment base pointers: lane l covers row (l&15), k-octet (l>>4)
    const float* pa[4];
    const uint16_t* pb[4];
    #pragma unroll
    for (int m = 0; m < 4; ++m) {
        int grow = m0 + wm * 64 + m * 16 + cl;
        if (grow >= N_NODES) grow = N_NODES - 1;   // tail clamp (stores guarded)
        pa[m] = A + (size_t)grow * K1 + kh * 8;
    }
    #pragma unroll
    for (int n = 0; n < 4; ++n) {
        int gcol = n0 + wn * 64 + n * 16 + cl;
        pb[n] = W1t + (size_t)gcol * K1 + kh * 8;
    }

    f32x4 acc[4][4];
    const f32x4 z = {0.f, 0.f, 0.f, 0.f};
    #pragma unroll
    for (int m = 0; m < 4; ++m)
        #pragma unroll
        for (int n = 0; n < 4; ++n) acc[m][n] = z;

    float4  a0[8], a1[8];      // fp32 A fragments, double-buffered
    bf16x8  b0[4], b1[4];      // bf16 B fragments, double-buffered

#define LOADA(S, KOFF) do {                                              \
    _Pragma("unroll")                                                    \
    for (int m = 0; m < 4; ++m) {                                        \
        S[2*m]   = *(const float4*)(pa[m] + (KOFF));                     \
        S[2*m+1] = *(const float4*)(pa[m] + (KOFF) + 4);                 \
    } } while (0)

#define LOADB(S, KOFF) do {                                              \
    _Pragma("unroll")                                                    \
    for (int n = 0; n < 4; ++n)                                          \
        S[n] = *(const bf16x8*)(pb[n] + (KOFF));                         \
    } while (0)

#define COMPUTE(SA, SB) do {                                             \
    bf16x8 af_[4];                                                       \
    _Pragma("unroll")                                                    \
    for (int m = 0; m < 4; ++m) {                                        \
        uint32_t uu_[4];                                                 \
        uu_[0] = cvt_pk_bf16(SA[2*m].x,   SA[2*m].y);                    \
        uu_[1] = cvt_pk_bf16(SA[2*m].z,   SA[2*m].w);                    \
        uu_[2] = cvt_pk_bf16(SA[2*m+1].x, SA[2*m+1].y);                  \
        uu_[3] = cvt_pk_bf16(SA[2*m+1].z, SA[2*m+1].w);                  \
        af_[m] = *(const bf16x8*)uu_;                                    \
    }                                                                    \
    _Pragma("unroll")                                                    \
    for (int m = 0; m < 4; ++m)                                          \
        _Pragma("unroll")                                                \
        for (int n = 0; n < 4; ++n)                                      \
            acc[m][n] = __builtin_amdgcn_mfma_f32_16x16x32_bf16(         \
                            af_[m], SB[n], acc[m][n], 0, 0, 0);          \
    } while (0)

    // prologue: K-steps 0 and 1 in flight
    LOADA(a0, 0);  LOADB(b0, 0);
    LOADA(a1, 32); LOADB(b1, 32);

    // steady state: 2 K-steps per iteration, prefetch 2 ahead (offsets are
    // compile-time immediates; pointers advance once per iteration)
    for (int i = 0; i < 11; ++i) {
        COMPUTE(a0, b0);
        LOADA(a0, 64); LOADB(b0, 64);
        COMPUTE(a1, b1);
        LOADA(a1, 96); LOADB(b1, 96);
        #pragma unroll
        for (int m = 0; m < 4; ++m) pa[m] += 64;
        #pragma unroll
        for (int n = 0; n < 4; ++n) pb[n] += 64;
    }
    COMPUTE(a0, b0);   // kt = 22
    COMPUTE(a1, b1);   // kt = 23

#undef LOADA
#undef LOADB
#undef COMPUTE

    // epilogue: +bias, relu, bf16 store.  C layout: col = lane&15, row = (lane>>4)*4 + reg
    float bv[4]; int bcol[4];
    #pragma unroll
    for (int n = 0; n < 4; ++n) { bcol[n] = n0 + wn * 64 + n * 16 + cl; bv[n] = bias1[bcol[n]]; }
    #pragma unroll
    for (int m = 0; m < 4; ++m) {
        int rbase = m0 + wm * 64 + m * 16 + kh * 4;
        #pragma unroll
        for (int rr = 0; rr < 4; ++rr) {
            int row = rbase + rr;
            if (row < N_NODES) {
                #pragma unroll
                for (int n = 0; n < 4; ++n) {
                    float v = acc[m][n][rr] + bv[n];
                    H[(size_t)row * D1 + bcol[n]] = f2bf(fmaxf(v, 0.f));
                }
            }
        }
    }
}

// ---- GEMM2: out[16384][97] = concat(H[head], H[tail]) @ Wp + bp ----
__global__ __launch_bounds__(256) void k_gemm2(const uint16_t* __restrict__ H,
        const uint16_t* __restrict__ Wpt, const float* __restrict__ bp,
        const int* __restrict__ head, const int* __restrict__ tail,
        float* __restrict__ out) {
    __shared__ uint16_t lds_w[NOUT_PAD][40];
    const int t = threadIdx.x;
    const int lane = t & 63, wave = t >> 6;
    const int cl = lane & 15, kh = lane >> 4;
    const int rowbase = blockIdx.x * 64 + wave * 16;
    const int i_l = rowbase + cl;
    const int nodeH = head[i_l], nodeT = tail[i_l];
    const uint16_t* hH = H + (size_t)nodeH * D1 + kh * 8;
    const uint16_t* hT = H + (size_t)nodeT * D1 + kh * 8;

    f32x4 acc[7];
    const f32x4 z = {0.f, 0.f, 0.f, 0.f};
    #pragma unroll
    for (int n = 0; n < 7; ++n) acc[n] = z;

    const int wrow = t >> 1, whalf = t & 1;
    const uint16_t* wsrc = Wpt + (size_t)wrow * 1024 + whalf * 16;
    uint16_t* wdst = &lds_w[wrow][whalf * 16];

    for (int kb = 0; kb < 32; ++kb) {
        uint4 w0 = {0,0,0,0}, w1 = {0,0,0,0};
        if (t < 224) {
            const uint4* wp4 = (const uint4*)(wsrc + kb * 32);
            w0 = wp4[0]; w1 = wp4[1];
        }
        bf16x8 af = (kb < 16) ? *(const bf16x8*)(hH + kb * 32)
                              : *(const bf16x8*)(hT + (kb - 16) * 32);
        __syncthreads();
        if (t < 224) { ((uint4*)wdst)[0] = w0; ((uint4*)wdst)[1] = w1; }
        __syncthreads();
        #pragma unroll
        for (int n = 0; n < 7; ++n) {
            bf16x8 bfr = *(const bf16x8*)&lds_w[n * 16 + cl][kh * 8];
            acc[n] = __builtin_amdgcn_mfma_f32_16x16x32_bf16(af, bfr, acc[n], 0, 0, 0);
        }
    }
    #pragma unroll
    for (int n = 0; n < 7; ++n) {
        int col = n * 16 + cl;
        if (col < NOUT) {
            float bb = bp[col];
            #pragma unroll
            for (int rr = 0; rr < 4; ++rr) {
                int i = rowbase + kh * 4 + rr;
                out[(size_t)i * NOUT + col] = acc[n][rr] + bb;
            }
        }
    }
}

extern "C" void kernel_launch(void* const* d_in, const int* in_sizes, int n_in,
                              void* d_out, int out_size, void* d_ws, size_t ws_size,
                              hipStream_t stream) {
    const float* node_features = (const float*)d_in[0];
    // d_in[1] = edge_features (unused: message passing is an exact identity)
    const float* W1   = (const float*)d_in[2];
    const float* b1   = (const float*)d_in[3];
    const float* Wp   = (const float*)d_in[4];
    const float* bp   = (const float*)d_in[5];
    // d_in[6] = src (unused), d_in[7] = dst (unused)
    const int* head   = (const int*)d_in[8];
    const int* tail   = (const int*)d_in[9];
    float* out = (float*)d_out;

    char* ws = (char*)d_ws;
    uint16_t* H   = (uint16_t*)ws;
    uint16_t* W1t = (uint16_t*)(ws + (size_t)N_NODES * D1 * 2);
    uint16_t* Wpt = (uint16_t*)(ws + (size_t)N_NODES * D1 * 2 + (size_t)D1 * K1 * 2);

    const int convN = D1 * K1 + NOUT_PAD * 1024;
    k_convert<<<(convN + 255) / 256, 256, 0, stream>>>(W1, Wp, W1t, Wpt);

    k_gemm1<<<WGPX * 8, 256, 0, stream>>>(node_features, W1t, b1, H);

    k_gemm2<<<NPAIR / 64, 256, 0, stream>>>(H, Wpt, bp, head, tail, out);
}

// Round 4
// 105.634 us; speedup vs baseline: 2.4189x; 2.4189x over previous
//
#include <hip/hip_runtime.h>
#include <hip/hip_bf16.h>
#include <stdint.h>

using bf16x8 = __attribute__((ext_vector_type(8))) short;
using f32x4  = __attribute__((ext_vector_type(4))) float;

#define N_NODES  50000
#define K1       768
#define D1       512
#define NPAIR    16384
#define NOUT     97
#define NOUT_PAD 112
#define MTILES   391                 // ceil(50000/128)
#define NTILES   4
#define NWG      (MTILES * NTILES)   // 1564
#define WGPX     196                 // ceil(1564/8)

__device__ __forceinline__ uint16_t f2bf(float f) {
    uint32_t u = __builtin_bit_cast(uint32_t, f);
    return (uint16_t)((u + 0x7fffu + ((u >> 16) & 1u)) >> 16);  // RNE
}

__device__ __forceinline__ uint32_t cvt_pk_bf16(float lo, float hi) {
    uint32_t r;
    asm("v_cvt_pk_bf16_f32 %0, %1, %2" : "=v"(r) : "v"(lo), "v"(hi));
    return r;
}

// async global->LDS DMA, 16B per lane; LDS dest = wave-uniform base + lane*16
__device__ __forceinline__ void gll16(const void* g, void* l) {
    __builtin_amdgcn_global_load_lds(
        (const __attribute__((address_space(1))) void*)g,
        (__attribute__((address_space(3))) void*)l, 16, 0, 0);
}

// ---- convert: W1[768][512] -> W1t bf16 [512][768]; Wp[1024][97] -> Wpt bf16 [112][1024] ----
__global__ void k_convert(const float* __restrict__ W1, const float* __restrict__ Wp,
                          uint16_t* __restrict__ W1t, uint16_t* __restrict__ Wpt) {
    int idx = blockIdx.x * 256 + threadIdx.x;
    const int n1 = D1 * K1;
    if (idx < n1) {
        int c = idx / K1, k = idx - c * K1;
        W1t[idx] = f2bf(W1[k * D1 + c]);
    } else {
        int j = idx - n1;
        if (j < NOUT_PAD * 1024) {
            int c = j >> 10, k = j & 1023;
            Wpt[j] = (c < NOUT) ? f2bf(Wp[k * NOUT + c]) : (uint16_t)0;
        }
    }
}

// ---- GEMM1: H[50000][512] = relu(A[50000][768] @ W1 + b1) ----
// m97 structure: 128x128 tile, BK=32, global_load_lds staging, single LDS buffer,
// 2 barriers/K-step. A kept fp32 in LDS (chunk-swizzled via source perm), cvt at read.
__global__ __launch_bounds__(256) void k_gemm1(const float* __restrict__ A,
        const uint16_t* __restrict__ W1t, const float* __restrict__ bias1,
        uint16_t* __restrict__ H) {
    __shared__ float    lds_a[4096];   // 128 rows x 32 fp32 (128B/row), chunks XOR-swizzled
    __shared__ uint16_t lds_b[4096];   // 128 rows x 32 bf16 (64B/row), linear

    const int bid = blockIdx.x;
    const int tt = (bid & 7) * WGPX + (bid >> 3);
    if (tt >= NWG) return;
    const int m0 = (tt >> 2) * 128, n0 = (tt & 3) * 128;

    const int t = threadIdx.x, lane = t & 63, w = t >> 6;
    const int wm = w >> 1, wn = w & 1;
    const int cl = lane & 15, kh = lane >> 4;
    const int l3 = lane >> 3, l7 = lane & 7;

    // --- staging sources. A instr i: lane writes LDS row w*32+i*8+l3, phys chunk l7;
    //     stored logical chunk must be l7 ^ (row&7) = l7 ^ (l3&7)  (source pre-swizzle)
    const float* aSrc[4];
    #pragma unroll
    for (int i = 0; i < 4; ++i) {
        int r = m0 + w * 32 + i * 8 + l3;
        if (r >= N_NODES) r = N_NODES - 1;   // tail clamp (stores guarded)
        aSrc[i] = A + (size_t)r * K1 + ((l7 ^ (l3 & 7)) * 4);
    }
    const uint16_t* bSrc[2];
    #pragma unroll
    for (int i = 0; i < 2; ++i)
        bSrc[i] = W1t + (size_t)(n0 + w * 32 + i * 16 + (lane >> 2)) * K1 + (lane & 3) * 8;

    float*    aDst = &lds_a[w * 1024];   // + i*256 floats (1KB per instr)
    uint16_t* bDst = &lds_b[w * 1024];   // + i*512 u16

    // --- fragment read offsets. A row's logical chunk c at phys c^(row&7); row&7 == lane&7
    const int q = lane & 7;
    const int pa0 = ((2 * kh) ^ q) * 4, pa1 = ((2 * kh + 1) ^ q) * 4;
    const int arow0 = (wm * 64 + cl) * 32;           // + m*512 (folds into ds offset imm)
    const int brow0 = (wn * 64 + cl) * 32 + kh * 8;  // + n*512

    f32x4 acc[4][4];
    const f32x4 z = {0.f, 0.f, 0.f, 0.f};
    #pragma unroll
    for (int m = 0; m < 4; ++m)
        #pragma unroll
        for (int n = 0; n < 4; ++n) acc[m][n] = z;

    for (int kt = 0; kt < K1 / 32; ++kt) {
        // stage tile kt (async DMA; end-of-iter barrier guarantees LDS is free)
        #pragma unroll
        for (int i = 0; i < 4; ++i) gll16(aSrc[i], aDst + i * 256);
        #pragma unroll
        for (int i = 0; i < 2; ++i) gll16(bSrc[i], bDst + i * 512);
        #pragma unroll
        for (int i = 0; i < 4; ++i) aSrc[i] += 32;
        #pragma unroll
        for (int i = 0; i < 2; ++i) bSrc[i] += 32;
        __syncthreads();   // drains vmcnt -> tile fully in LDS

        bf16x8 af[4], bfr[4];
        #pragma unroll
        for (int m = 0; m < 4; ++m) {
            f32x4 r0 = *(const f32x4*)&lds_a[arow0 + m * 512 + pa0];
            f32x4 r1 = *(const f32x4*)&lds_a[arow0 + m * 512 + pa1];
            uint32_t uu[4];
            uu[0] = cvt_pk_bf16(r0[0], r0[1]);
            uu[1] = cvt_pk_bf16(r0[2], r0[3]);
            uu[2] = cvt_pk_bf16(r1[0], r1[1]);
            uu[3] = cvt_pk_bf16(r1[2], r1[3]);
            af[m] = *(const bf16x8*)uu;
        }
        #pragma unroll
        for (int n = 0; n < 4; ++n)
            bfr[n] = *(const bf16x8*)&lds_b[brow0 + n * 512];
        #pragma unroll
        for (int m = 0; m < 4; ++m)
            #pragma unroll
            for (int n = 0; n < 4; ++n)
                acc[m][n] = __builtin_amdgcn_mfma_f32_16x16x32_bf16(af[m], bfr[n], acc[m][n], 0, 0, 0);
        __syncthreads();   // all reads done before next stage overwrites
    }

    // epilogue: +bias, relu, bf16 store.  C layout: col = lane&15, row = (lane>>4)*4 + reg
    float bv[4]; int bcol[4];
    #pragma unroll
    for (int n = 0; n < 4; ++n) { bcol[n] = n0 + wn * 64 + n * 16 + cl; bv[n] = bias1[bcol[n]]; }
    #pragma unroll
    for (int m = 0; m < 4; ++m) {
        int rbase = m0 + wm * 64 + m * 16 + kh * 4;
        #pragma unroll
        for (int rr = 0; rr < 4; ++rr) {
            int row = rbase + rr;
            if (row < N_NODES) {
                #pragma unroll
                for (int n = 0; n < 4; ++n) {
                    float v = acc[m][n][rr] + bv[n];
                    H[(size_t)row * D1 + bcol[n]] = f2bf(fmaxf(v, 0.f));
                }
            }
        }
    }
}

// ---- GEMM2: out[16384][97] = concat(H[head], H[tail]) @ Wp + bp ----
__global__ __launch_bounds__(256) void k_gemm2(const uint16_t* __restrict__ H,
        const uint16_t* __restrict__ Wpt, const float* __restrict__ bp,
        const int* __restrict__ head, const int* __restrict__ tail,
        float* __restrict__ out) {
    __shared__ uint16_t lds_w[NOUT_PAD][40];
    const int t = threadIdx.x;
    const int lane = t & 63, wave = t >> 6;
    const int cl = lane & 15, kh = lane >> 4;
    const int rowbase = blockIdx.x * 64 + wave * 16;
    const int i_l = rowbase + cl;
    const int nodeH = head[i_l], nodeT = tail[i_l];
    const uint16_t* hH = H + (size_t)nodeH * D1 + kh * 8;
    const uint16_t* hT = H + (size_t)nodeT * D1 + kh * 8;

    f32x4 acc[7];
    const f32x4 z = {0.f, 0.f, 0.f, 0.f};
    #pragma unroll
    for (int n = 0; n < 7; ++n) acc[n] = z;

    const int wrow = t >> 1, whalf = t & 1;
    const uint16_t* wsrc = Wpt + (size_t)wrow * 1024 + whalf * 16;
    uint16_t* wdst = &lds_w[wrow][whalf * 16];

    for (int kb = 0; kb < 32; ++kb) {
        uint4 w0 = {0,0,0,0}, w1 = {0,0,0,0};
        if (t < 224) {
            const uint4* wp4 = (const uint4*)(wsrc + kb * 32);
            w0 = wp4[0]; w1 = wp4[1];
        }
        bf16x8 af = (kb < 16) ? *(const bf16x8*)(hH + kb * 32)
                              : *(const bf16x8*)(hT + (kb - 16) * 32);
        __syncthreads();
        if (t < 224) { ((uint4*)wdst)[0] = w0; ((uint4*)wdst)[1] = w1; }
        __syncthreads();
        #pragma unroll
        for (int n = 0; n < 7; ++n) {
            bf16x8 bfr = *(const bf16x8*)&lds_w[n * 16 + cl][kh * 8];
            acc[n] = __builtin_amdgcn_mfma_f32_16x16x32_bf16(af, bfr, acc[n], 0, 0, 0);
        }
    }
    #pragma unroll
    for (int n = 0; n < 7; ++n) {
        int col = n * 16 + cl;
        if (col < NOUT) {
            float bb = bp[col];
            #pragma unroll
            for (int rr = 0; rr < 4; ++rr) {
                int i = rowbase + kh * 4 + rr;
                out[(size_t)i * NOUT + col] = acc[n][rr] + bb;
            }
        }
    }
}

extern "C" void kernel_launch(void* const* d_in, const int* in_sizes, int n_in,
                              void* d_out, int out_size, void* d_ws, size_t ws_size,
                              hipStream_t stream) {
    const float* node_features = (const float*)d_in[0];
    // d_in[1] = edge_features (unused: message passing is an exact identity)
    const float* W1   = (const float*)d_in[2];
    const float* b1   = (const float*)d_in[3];
    const float* Wp   = (const float*)d_in[4];
    const float* bp   = (const float*)d_in[5];
    // d_in[6] = src (unused), d_in[7] = dst (unused)
    const int* head   = (const int*)d_in[8];
    const int* tail   = (const int*)d_in[9];
    float* out = (float*)d_out;

    char* ws = (char*)d_ws;
    uint16_t* H   = (uint16_t*)ws;
    uint16_t* W1t = (uint16_t*)(ws + (size_t)N_NODES * D1 * 2);
    uint16_t* Wpt = (uint16_t*)(ws + (size_t)N_NODES * D1 * 2 + (size_t)D1 * K1 * 2);

    const int convN = D1 * K1 + NOUT_PAD * 1024;
    k_convert<<<(convN + 255) / 256, 256, 0, stream>>>(W1, Wp, W1t, Wpt);

    k_gemm1<<<WGPX * 8, 256, 0, stream>>>(node_features, W1t, b1, H);

    k_gemm2<<<NPAIR / 64, 256, 0, stream>>>(H, Wpt, bp, head, tail, out);
}